// Round 8
// baseline (99.443 us; speedup 1.0000x reference)
//
#include <hip/hip_runtime.h>

typedef __attribute__((ext_vector_type(8))) short short8;
typedef __attribute__((ext_vector_type(16))) float f32x16;

#define MFMA32 __builtin_amdgcn_mfma_f32_32x32x16_bf16

__device__ __forceinline__ unsigned short f2bf(float f) {
  unsigned int u = __float_as_uint(f);
  u += 0x7fffu + ((u >> 16) & 1u);
  return (unsigned short)(u >> 16);
}

// Pre-pack the 6 weight matrices fp32 [k][n] -> bf16 MFMA-fragment order,
// replicated REP times (replica r at byte offset r*768KB):
// wt[(((s*6 + g)*8 + c)*64 + l)*8 + j] = G_g[k][n]
//   with k = s*16 + (l>>5)*8 + j, n = c*32 + (l&31)
__global__ __launch_bounds__(256) void wprep(
    const float* __restrict__ Wu, const float* __restrict__ Wr, const float* __restrict__ Wh,
    const float* __restrict__ Uu, const float* __restrict__ Ur, const float* __restrict__ Uh,
    unsigned short* __restrict__ wt) {
  int rep = blockIdx.x / 1536;
  int idx = (blockIdx.x % 1536) * 256 + threadIdx.x;   // 0 .. 6*65536-1
  int j = idx & 7;
  int l = (idx >> 3) & 63;
  int c = (idx >> 9) & 7;
  int sg = idx >> 12;
  int g = sg % 6;
  int s = sg / 6;
  int k = s * 16 + (l >> 5) * 8 + j;
  int n = c * 32 + (l & 31);
  const float* src = (g == 0) ? Wu : (g == 1) ? Wr : (g == 2) ? Wh
                   : (g == 3) ? Uu : (g == 4) ? Ur : Uh;
  wt[rep * 6 * 65536 + idx] = f2bf(src[k * 256 + n]);
}

// Fused AUGRU. Block = 512 thr (8 waves), tile 64 rows x 256 cols.
// Wave w owns cols [32w, 32w+32), all 64 rows, mfma 32x32x16.
// Weights: global->VGPR ring, depth 4. Slab order staggered per block;
// each block reads weight replica (bid % nrep). No barriers in K-loops.
__global__ __launch_bounds__(512, 2) void augru_main(
    const float* __restrict__ x, const float* __restrict__ h1,
    const float* __restrict__ a, const unsigned short* __restrict__ wt,
    const float* __restrict__ bu, const float* __restrict__ br,
    const float* __restrict__ bh, float* __restrict__ out, int nrep) {
  extern __shared__ char smem[];
  char* lX = smem;                       // 32768 B x tile bf16, swizzled
  char* lH = smem + 32768;               // 32768 B h tile bf16, swizzled
  float* a_s = (float*)(smem + 65536);   // 64 floats

  const int tid = threadIdx.x;
  const int l   = tid & 63;
  const int wid = tid >> 6;          // 0..7 -> 32-col chunk
  const int fr  = l & 31;            // row (A) / col (B,C)
  const int fq  = l >> 5;            // k-half (A/B) / row+4 group (C)
  const long rowbase = (long)blockIdx.x * 64;
  const int aswz = (fr & 7) << 4;
  const int n = wid * 32 + fr;
  const int rot = (int)(blockIdx.x * 5) & 15;    // slab stagger

  const char* wb = (const char*)wt + (long)(blockIdx.x % nrep) * (6 * 65536 * 2)
                   + (wid << 10) + (l << 4);
#define WOFF(SG) ((SG) << 13)

  // ---- issue x tile loads (all 8 up front: max MLP) ----
  const float* xsrc = x + rowbase * 256;
  float4 xv[8];
#pragma unroll
  for (int i = 0; i < 8; ++i) xv[i] = ((const float4*)xsrc)[i * 512 + tid];

  // ---- prefetch W ring: positions 0..3 = x-gates of slabs (p+rot)&15 ----
  short8 W[4][3];
#pragma unroll
  for (int p = 0; p < 4; ++p) {
    const int sg = (((p + rot) & 15)) * 6;
#pragma unroll
    for (int g = 0; g < 3; ++g)
      W[p][g] = *(const short8*)(wb + WOFF(sg + g));
  }

  // ---- issue first half of h tile loads ----
  const float* hsrc = h1 + rowbase * 256;
  float4 hv[8];
#pragma unroll
  for (int i = 0; i < 4; ++i) hv[i] = ((const float4*)hsrc)[i * 512 + tid];

  const float vbu = bu[n], vbr = br[n], vbh = bh[n];
  if (tid < 64) a_s[tid] = a[rowbase + tid];

  // ---- convert + write x tile (swizzled: byte ^= (row&7)<<4) ----
#pragma unroll
  for (int i = 0; i < 8; ++i) {
    int f   = i * 512 + tid;
    int row = f >> 6;
    int kq  = f & 63;
    ushort4 b;
    b.x = f2bf(xv[i].x); b.y = f2bf(xv[i].y); b.z = f2bf(xv[i].z); b.w = f2bf(xv[i].w);
    *(ushort4*)(lX + (row << 9) + ((kq * 8) ^ ((row & 7) << 4))) = b;
  }
  __syncthreads();   // lX ready

#define HWRITE(I)                                                           \
  {                                                                         \
    int f = (I) * 512 + tid;                                                \
    int row = f >> 6;                                                       \
    int kq = f & 63;                                                        \
    ushort4 b;                                                              \
    b.x = f2bf(hv[I].x); b.y = f2bf(hv[I].y);                               \
    b.z = f2bf(hv[I].z); b.w = f2bf(hv[I].w);                               \
    *(ushort4*)(lH + (row << 9) + ((kq * 8) ^ ((row & 7) << 4))) = b;       \
  }

  f32x16 accU0 = {}, accU1 = {};
  f32x16 accR0 = {}, accR1 = {};
  f32x16 accXH0 = {}, accXH1 = {};
  f32x16 accHH0 = {}, accHH1 = {};

  // ---- x-pass: positions 0..15 -> slab (p+rot)&15, gates 0-2. ----
#pragma unroll
  for (int p = 0; p < 16; ++p) {
    const int s = (p + rot) & 15;
    const int koff = ((s << 5) + (fq << 4)) ^ aswz;
    short8 ax0 = *(const short8*)(lX + (fr << 9) + koff);
    short8 ax1 = *(const short8*)(lX + ((fr + 32) << 9) + koff);
    accU0  = MFMA32(ax0, W[p & 3][0], accU0, 0, 0, 0);
    accU1  = MFMA32(ax1, W[p & 3][0], accU1, 0, 0, 0);
    accR0  = MFMA32(ax0, W[p & 3][1], accR0, 0, 0, 0);
    accR1  = MFMA32(ax1, W[p & 3][1], accR1, 0, 0, 0);
    accXH0 = MFMA32(ax0, W[p & 3][2], accXH0, 0, 0, 0);
    accXH1 = MFMA32(ax1, W[p & 3][2], accXH1, 0, 0, 0);
    // refill ring slot (p&3) for position p+4; roll into h-gate positions
    const int q = p + 4;
    const int sg = (q < 16) ? (((q + rot) & 15)) * 6
                            : (((q - 16 + rot) & 15)) * 6 + 3;
#pragma unroll
    for (int g = 0; g < 3; ++g)
      W[p & 3][g] = *(const short8*)(wb + WOFF(sg + g));
    if (p == 4) {
#pragma unroll
      for (int i = 4; i < 8; ++i) hv[i] = ((const float4*)hsrc)[i * 512 + tid];
    }
    if (p == 8)  { HWRITE(0) HWRITE(1) HWRITE(2) HWRITE(3) }
    if (p == 12) { HWRITE(4) HWRITE(5) HWRITE(6) HWRITE(7) }
  }
  __syncthreads();   // lH ready

  // ---- h-pass: positions 0..15 -> slab (p+rot)&15, gates 3-5. ----
#pragma unroll
  for (int p = 0; p < 16; ++p) {
    const int s = (p + rot) & 15;
    const int koff = ((s << 5) + (fq << 4)) ^ aswz;
    short8 ah0 = *(const short8*)(lH + (fr << 9) + koff);
    short8 ah1 = *(const short8*)(lH + ((fr + 32) << 9) + koff);
    accU0  = MFMA32(ah0, W[p & 3][0], accU0, 0, 0, 0);
    accU1  = MFMA32(ah1, W[p & 3][0], accU1, 0, 0, 0);
    accR0  = MFMA32(ah0, W[p & 3][1], accR0, 0, 0, 0);
    accR1  = MFMA32(ah1, W[p & 3][1], accR1, 0, 0, 0);
    accHH0 = MFMA32(ah0, W[p & 3][2], accHH0, 0, 0, 0);
    accHH1 = MFMA32(ah1, W[p & 3][2], accHH1, 0, 0, 0);
    const int q = p + 4;
    if (q < 16) {
      const int sg = (((q + rot) & 15)) * 6 + 3;
#pragma unroll
      for (int g = 0; g < 3; ++g)
        W[p & 3][g] = *(const short8*)(wb + WOFF(sg + g));
    }
  }

  // ---- epilogue: coalesced fp32 h1 re-read (L2-hot), light gate math ----
  const float* hcol = h1 + rowbase * 256 + n;
  float* ocol = out + rowbase * 256 + n;
  float hE0[16], hE1[16];
#pragma unroll
  for (int g8 = 0; g8 < 4; ++g8)
#pragma unroll
    for (int j = 0; j < 4; ++j) {
      const int rl = g8 * 8 + fq * 4 + j;
      hE0[g8 * 4 + j] = hcol[(long)rl * 256];
      hE1[g8 * 4 + j] = hcol[(long)(rl + 32) * 256];
    }

#define EPI(ACCU, ACCR, ACCXH, ACCHH, HE, RB)                               \
  _Pragma("unroll")                                                         \
  for (int g8 = 0; g8 < 4; ++g8) {                                          \
    _Pragma("unroll")                                                       \
    for (int j = 0; j < 4; ++j) {                                           \
      const int reg = g8 * 4 + j;                                           \
      const int rl  = (RB) + g8 * 8 + fq * 4 + j;                           \
      const float pu = ACCU[reg] + vbu;                                     \
      const float pr = ACCR[reg] + vbr;                                     \
      const float uu = __builtin_amdgcn_rcpf(1.f + __expf(-pu));            \
      const float rr = __builtin_amdgcn_rcpf(1.f + __expf(-pr));            \
      const float cc = fmaf(rr, ACCHH[reg], ACCXH[reg]) + vbh;              \
      const float tt = __builtin_amdgcn_rcpf(1.f + __expf(-2.f * cc));      \
      const float th = fmaf(2.f, tt, -1.f);                                 \
      const float uh = a_s[rl] * uu;                                        \
      const float h1v = HE[reg];                                            \
      ocol[(long)rl * 256] = fmaf(uh, th - h1v, h1v);                       \
    }                                                                       \
  }

  EPI(accU0, accR0, accXH0, accHH0, hE0, 0)
  EPI(accU1, accR1, accXH1, accHH1, hE1, 32)
#undef EPI
#undef HWRITE
#undef WOFF
}

extern "C" void kernel_launch(void* const* d_in, const int* in_sizes, int n_in,
                              void* d_out, int out_size, void* d_ws, size_t ws_size,
                              hipStream_t stream) {
  const float* x  = (const float*)d_in[0];
  const float* h1 = (const float*)d_in[1];
  const float* a  = (const float*)d_in[2];
  const float* Wu = (const float*)d_in[3];
  const float* Uu = (const float*)d_in[4];
  const float* bu = (const float*)d_in[5];
  const float* Wr = (const float*)d_in[6];
  const float* Ur = (const float*)d_in[7];
  const float* br = (const float*)d_in[8];
  const float* Wh = (const float*)d_in[9];
  const float* Uh = (const float*)d_in[10];
  const float* bh = (const float*)d_in[11];
  unsigned short* wt = (unsigned short*)d_ws;

  // replicate packed weights to spread L2 pressure; replica = 768 KB
  int nrep = (int)(ws_size / (6 * 65536 * sizeof(unsigned short)));
  if (nrep < 1) nrep = 1;
  if (nrep > 8) nrep = 8;

  wprep<<<1536 * nrep, 256, 0, stream>>>(Wu, Wr, Wh, Uu, Ur, Uh, wt);

  const int lds_bytes = 65536 + 256;
  hipFuncSetAttribute((const void*)augru_main,
                      hipFuncAttributeMaxDynamicSharedMemorySize, lds_bytes);

  const int rows = in_sizes[0] / 256;           // 65536
  augru_main<<<rows / 64, 512, lds_bytes, stream>>>(x, h1, a, wt, bu, br, bh,
                                                    (float*)d_out, nrep);
}